// Round 1
// baseline (58.617 us; speedup 1.0000x reference)
//
#include <hip/hip_runtime.h>

// TweetRep: x (8,6,32,32,30) int32 indices, embeddings (50000,64) f32.
// out (8, 6*64, 32, 32) f32.
// One wave (64 lanes) per pixel; lane = embedding dim. Cross-lane dot
// reductions done with DPP adds (VALU pipe), not shfl (LDS pipe).

#define LTOK 30
#define EMBD 64
#define NPIX (8 * 6 * 32 * 32)   // 49152

template <int CTRL, int RM>
__device__ __forceinline__ float dppadd(float v) {
    // v += dpp_permute(v); masked-off rows add 0 (old = 0, bound_ctrl = 1)
    int s = __builtin_amdgcn_update_dpp(0, __float_as_int(v), CTRL, RM, 0xF, true);
    return v + __int_as_float(s);
}

__global__ __launch_bounds__(256) void tweetrep_kernel(
        const int* __restrict__ x, const float* __restrict__ emb,
        float* __restrict__ out)
{
    const int lane = threadIdx.x & 63;
    int pixel = (blockIdx.x << 2) | (threadIdx.x >> 6);
    pixel = __builtin_amdgcn_readfirstlane(pixel);   // wave-uniform -> scalar loads
    if (pixel >= NPIX) return;

    const int* xp = x + pixel * LTOK;

    // Gather 30 embedding rows; lane e holds dim e. 256B coalesced per load.
    float wg[LTOK];
    float V = 0.f;
#pragma unroll
    for (int l = 0; l < LTOK; ++l) {
        const int idx = xp[l];                       // scalar (uniform) load
        wg[l] = emb[(size_t)idx * EMBD + lane];
        V += wg[l];
    }

    // b_l = wave-sum over lanes of wg[l] * V   (DPP butterfly + bcast, lane63)
    float b[LTOK];
#pragma unroll
    for (int l = 0; l < LTOK; ++l) {
        float p = wg[l] * V;
        p = dppadd<0xB1,  0xF>(p);   // quad_perm {1,0,3,2}  : xor 1
        p = dppadd<0x4E,  0xF>(p);   // quad_perm {2,3,0,1}  : xor 2
        p = dppadd<0x141, 0xF>(p);   // row_half_mirror      : pair quads
        p = dppadd<0x140, 0xF>(p);   // row_mirror           : pair 8s
        p = dppadd<0x142, 0xA>(p);   // row_bcast15 -> rows 1,3
        p = dppadd<0x143, 0xC>(p);   // row_bcast31 -> rows 2,3
        b[l] = __int_as_float(
                   __builtin_amdgcn_readlane(__float_as_int(p), 63));
    }

    // softmax over the 30 scores (uniform across lanes; cheap)
    float m = b[0];
#pragma unroll
    for (int l = 1; l < LTOK; ++l) m = fmaxf(m, b[l]);
    float ssum = 0.f;
#pragma unroll
    for (int l = 0; l < LTOK; ++l) { b[l] = __expf(b[l] - m); ssum += b[l]; }
    const float inv = __builtin_amdgcn_rcpf(ssum);

    // attention-pooled rep for this lane's dim
    float ws = 0.f;
#pragma unroll
    for (int l = 0; l < LTOK; ++l) ws = fmaf(wg[l], b[l], ws);
    ws *= inv;

    // out[b][t*64 + e][h][w]: pixel = bt*1024 + hw
    const int bt = pixel >> 10;
    const int hw = pixel & 1023;
    out[((size_t)(bt * EMBD + lane) << 10) | (size_t)hw] = ws;
}

extern "C" void kernel_launch(void* const* d_in, const int* in_sizes, int n_in,
                              void* d_out, int out_size, void* d_ws, size_t ws_size,
                              hipStream_t stream)
{
    const int*   x   = (const int*)d_in[0];
    const float* emb = (const float*)d_in[1];
    float*       out = (float*)d_out;

    const int blocks = NPIX / 4;   // 4 waves (pixels) per 256-thread block
    tweetrep_kernel<<<blocks, 256, 0, stream>>>(x, emb, out);
}

// Round 2
// 47.290 us; speedup vs baseline: 1.2395x; 1.2395x over previous
//
#include <hip/hip_runtime.h>

// TweetRep: x (8,6,32,32,30) int32, embeddings (50000,64) f32 -> out (8,384,32,32) f32.
// 4 pixels per wave: 16-lane groups, each lane holds 4 embedding dims (float4).
// Cross-lane dots reduced with 4 DPP steps within the 16-lane group; all
// per-token scalar work (softmax, exp, index math) amortized over 4 pixels.

#define LTOK 30
#define NPIX (8 * 6 * 32 * 32)   // 49152
#define L2E  1.4426950408889634f

template <int CTRL>
__device__ __forceinline__ float dppadd(float v) {
    // v += dpp_permute(v), full row/bank masks (all lanes written)
    int t = __builtin_amdgcn_update_dpp(0, __float_as_int(v), CTRL, 0xF, 0xF, true);
    return v + __int_as_float(t);
}

__global__ __launch_bounds__(256, 3) void tweetrep_kernel(
        const int* __restrict__ x, const float* __restrict__ emb,
        float* __restrict__ out)
{
    const int lane16 = threadIdx.x & 15;
    const int pix    = (blockIdx.x << 4) | (threadIdx.x >> 4);  // 16 pixels/block

    // ---- indices: 15 x dwordx2, uniform within each 16-lane group ----
    const int* xp = x + pix * LTOK;
    int idx[LTOK];
#pragma unroll
    for (int l = 0; l < LTOK; l += 2) {
        int2 ii = *reinterpret_cast<const int2*>(xp + l);
        idx[l] = ii.x; idx[l + 1] = ii.y;
    }

    // ---- gather 30 rows, lane holds dims [4*lane16, 4*lane16+4) ----
    float4 wg[LTOK];
    float4 V = make_float4(0.f, 0.f, 0.f, 0.f);
#pragma unroll
    for (int l = 0; l < LTOK; ++l) {
        wg[l] = *reinterpret_cast<const float4*>(
                    emb + ((size_t)idx[l] << 6) + (lane16 << 2));
        V.x += wg[l].x; V.y += wg[l].y; V.z += wg[l].z; V.w += wg[l].w;
    }

    // ---- b_l = <wg_l, V> : 4 per-lane FMAs + 4 DPP adds within 16 lanes ----
    float b[LTOK];
#pragma unroll
    for (int l = 0; l < LTOK; ++l) {
        float p = wg[l].x * V.x;
        p = fmaf(wg[l].y, V.y, p);
        p = fmaf(wg[l].z, V.z, p);
        p = fmaf(wg[l].w, V.w, p);
        p = dppadd<0xB1>(p);    // quad_perm {1,0,3,2} : xor 1
        p = dppadd<0x4E>(p);    // quad_perm {2,3,0,1} : xor 2
        p = dppadd<0x141>(p);   // row_half_mirror    : pair quads (8)
        p = dppadd<0x140>(p);   // row_mirror         : pair 8s   (16)
        b[l] = p;
    }

    // ---- softmax over 30 (uniform within group) ----
    float m0 = b[0], m1 = b[1], m2 = b[2], m3 = b[3];
#pragma unroll
    for (int l = 4; l + 3 < LTOK; l += 4) {
        m0 = fmaxf(m0, b[l]);     m1 = fmaxf(m1, b[l + 1]);
        m2 = fmaxf(m2, b[l + 2]); m3 = fmaxf(m3, b[l + 3]);
    }
    m0 = fmaxf(m0, b[28]); m1 = fmaxf(m1, b[29]);
    const float m  = fmaxf(fmaxf(m0, m1), fmaxf(m2, m3));
    const float nm = -m * L2E;

    float s0 = 0.f, s1 = 0.f;
#pragma unroll
    for (int l = 0; l < LTOK; l += 2) {
        b[l]     = __builtin_exp2f(fmaf(b[l],     L2E, nm));
        b[l + 1] = __builtin_exp2f(fmaf(b[l + 1], L2E, nm));
        s0 += b[l]; s1 += b[l + 1];
    }
    const float inv = __builtin_amdgcn_rcpf(s0 + s1);

    // ---- attention-pooled rep for this lane's 4 dims ----
    float4 ws = make_float4(0.f, 0.f, 0.f, 0.f);
#pragma unroll
    for (int l = 0; l < LTOK; ++l) {
        ws.x = fmaf(b[l], wg[l].x, ws.x);
        ws.y = fmaf(b[l], wg[l].y, ws.y);
        ws.z = fmaf(b[l], wg[l].z, ws.z);
        ws.w = fmaf(b[l], wg[l].w, ws.w);
    }

    // ---- out[bt*64 + e][hw], e = 4*lane16 + j ----
    const int bt = pix >> 10, hw = pix & 1023;
    float* op = out + (((size_t)(bt * 64 + (lane16 << 2))) << 10) + hw;
    op[0]    = ws.x * inv;
    op[1024] = ws.y * inv;
    op[2048] = ws.z * inv;
    op[3072] = ws.w * inv;
}

extern "C" void kernel_launch(void* const* d_in, const int* in_sizes, int n_in,
                              void* d_out, int out_size, void* d_ws, size_t ws_size,
                              hipStream_t stream)
{
    const int*   x   = (const int*)d_in[0];
    const float* emb = (const float*)d_in[1];
    float*       out = (float*)d_out;

    const int blocks = NPIX / 16;   // 16 pixels per 256-thread block
    tweetrep_kernel<<<blocks, 256, 0, stream>>>(x, emb, out);
}

// Round 3
// 47.242 us; speedup vs baseline: 1.2408x; 1.0010x over previous
//
#include <hip/hip_runtime.h>

// TweetRep: x (8,6,32,32,30) int32, embeddings (50000,64) f32 -> out (8,384,32,32) f32.
// 4 pixels per wave: 16-lane groups, each lane holds 4 embedding dims (float4).
// Round-3 change: pin wg[30] (the gathered rows) in VGPRs via asm barriers so
// the compiler cannot re-gather them in the ws pass (round-2 did the gather
// twice: VGPR=84 < 120 needed, FETCH 135MB ~= 2x table stream).

#define LTOK 30
#define NPIX (8 * 6 * 32 * 32)   // 49152
#define L2E  1.4426950408889634f

template <int CTRL>
__device__ __forceinline__ float dppadd(float v) {
    // v += dpp_permute(v), full row/bank masks; folds to v_add_f32_dpp
    int t = __builtin_amdgcn_update_dpp(0, __float_as_int(v), CTRL, 0xF, 0xF, true);
    return v + __int_as_float(t);
}

__global__ __launch_bounds__(256) void tweetrep_kernel(
        const int* __restrict__ x, const float* __restrict__ emb,
        float* __restrict__ out)
{
    const int lane16 = threadIdx.x & 15;
    const int pix    = (blockIdx.x << 4) | (threadIdx.x >> 4);  // 16 pixels/block

    // ---- indices: 7x dwordx4 + 1x dwordx2, uniform within each 16-lane group
    const int* xp = x + pix * LTOK;
    int idx[LTOK];
#pragma unroll
    for (int l = 0; l < 28; l += 4) {
        int4 ii = *reinterpret_cast<const int4*>(xp + l);
        idx[l] = ii.x; idx[l + 1] = ii.y; idx[l + 2] = ii.z; idx[l + 3] = ii.w;
    }
    { int2 ii = *reinterpret_cast<const int2*>(xp + 28); idx[28] = ii.x; idx[29] = ii.y; }

    // ---- gather 30 rows once; lane holds dims [4*lane16, 4*lane16+4) ----
    float4 wg[LTOK];
#pragma unroll
    for (int l = 0; l < LTOK; ++l)
        wg[l] = *reinterpret_cast<const float4*>(
                    emb + ((size_t)idx[l] << 6) + (lane16 << 2));

    // Pin every gathered value in a VGPR: forbids rematerializing the loads.
#pragma unroll
    for (int l = 0; l < LTOK; ++l)
        asm volatile("" : "+v"(wg[l].x), "+v"(wg[l].y), "+v"(wg[l].z), "+v"(wg[l].w));

    float4 V = make_float4(0.f, 0.f, 0.f, 0.f);
#pragma unroll
    for (int l = 0; l < LTOK; ++l) {
        V.x += wg[l].x; V.y += wg[l].y; V.z += wg[l].z; V.w += wg[l].w;
    }

    // ---- b_l = <wg_l, V> : 4 per-lane FMAs + 4 DPP adds within 16 lanes ----
    float b[LTOK];
#pragma unroll
    for (int l = 0; l < LTOK; ++l) {
        float p = wg[l].x * V.x;
        p = fmaf(wg[l].y, V.y, p);
        p = fmaf(wg[l].z, V.z, p);
        p = fmaf(wg[l].w, V.w, p);
        p = dppadd<0xB1>(p);    // quad_perm {1,0,3,2} : xor 1
        p = dppadd<0x4E>(p);    // quad_perm {2,3,0,1} : xor 2
        p = dppadd<0x141>(p);   // row_half_mirror    : pair quads (8)
        p = dppadd<0x140>(p);   // row_mirror         : pair 8s   (16)
        b[l] = p;
    }

    // ---- softmax over 30 (uniform within group) ----
    float m0 = b[0], m1 = b[1], m2 = b[2], m3 = b[3];
#pragma unroll
    for (int l = 4; l + 3 < LTOK; l += 4) {
        m0 = fmaxf(m0, b[l]);     m1 = fmaxf(m1, b[l + 1]);
        m2 = fmaxf(m2, b[l + 2]); m3 = fmaxf(m3, b[l + 3]);
    }
    m0 = fmaxf(m0, b[28]); m1 = fmaxf(m1, b[29]);
    const float m  = fmaxf(fmaxf(m0, m1), fmaxf(m2, m3));
    const float nm = -m * L2E;

    float s0 = 0.f, s1 = 0.f;
#pragma unroll
    for (int l = 0; l < LTOK; l += 2) {
        b[l]     = __builtin_exp2f(fmaf(b[l],     L2E, nm));
        b[l + 1] = __builtin_exp2f(fmaf(b[l + 1], L2E, nm));
        s0 += b[l]; s1 += b[l + 1];
    }
    const float inv = __builtin_amdgcn_rcpf(s0 + s1);

    // ---- attention-pooled rep for this lane's 4 dims (wg still in regs) ----
    float4 ws = make_float4(0.f, 0.f, 0.f, 0.f);
#pragma unroll
    for (int l = 0; l < LTOK; ++l) {
        ws.x = fmaf(b[l], wg[l].x, ws.x);
        ws.y = fmaf(b[l], wg[l].y, ws.y);
        ws.z = fmaf(b[l], wg[l].z, ws.z);
        ws.w = fmaf(b[l], wg[l].w, ws.w);
    }

    // ---- out[bt*64 + e][hw], e = 4*lane16 + j ----
    const int bt = pix >> 10, hw = pix & 1023;
    float* op = out + (((size_t)(bt * 64 + (lane16 << 2))) << 10) + hw;
    op[0]    = ws.x * inv;
    op[1024] = ws.y * inv;
    op[2048] = ws.z * inv;
    op[3072] = ws.w * inv;
}

extern "C" void kernel_launch(void* const* d_in, const int* in_sizes, int n_in,
                              void* d_out, int out_size, void* d_ws, size_t ws_size,
                              hipStream_t stream)
{
    const int*   x   = (const int*)d_in[0];
    const float* emb = (const float*)d_in[1];
    float*       out = (float*)d_out;

    const int blocks = NPIX / 16;   // 16 pixels per 256-thread block
    tweetrep_kernel<<<blocks, 256, 0, stream>>>(x, emb, out);
}